// Round 1
// baseline (126.044 us; speedup 1.0000x reference)
//
#include <hip/hip_runtime.h>

// MLP_Interpolate: B=4, C=64, H=W=128, out 512x512, n_feat=64.
// Key algebra: 4x nearest upsample => iy = oy>>2, ix = ox>>2 exactly;
// rel_y/rel_x depend only on (oy&3)/(ox&3), values (2r-3)/4.
// So per INPUT pixel: f[j] = b1[j] + sum_c x[b,c,k,l] * W1[c,j]  (once),
// then 16 subpixels: h = relu(f + ay*W1[64,:] + ax*W1[65,:]); pred = h@W2 + b2.

#define PLANE (512 * 512)

__global__ __launch_bounds__(64) void mlp_interp_kernel(
    const float* __restrict__ x,   // [4,64,128,128]
    const float* __restrict__ W1,  // [66,64]
    const float* __restrict__ b1,  // [64]
    const float* __restrict__ W2,  // [64,3]
    const float* __restrict__ b2,  // [3]
    float* __restrict__ out)       // [4,3,512,512]
{
    __shared__ float xs[64][64];   // [c][l]  16 KiB

    const int t    = threadIdx.x;        // 0..63, owns input pixel l0+t
    const int blk  = blockIdx.x;         // 0..1023
    const int lblk = blk & 1;            // W/64 = 2 strips
    const int k    = (blk >> 1) & 127;   // input row
    const int b    = blk >> 8;           // batch
    const int l0   = lblk * 64;

    // ---- stage x tile [c][l0..l0+63] into LDS, float4-coalesced ----
    {
        const float* xrow = x + (((size_t)(b * 64) * 128 + k) * 128 + l0);
        const int lq = (t & 15) * 4;   // column quad
        const int cb = t >> 4;         // 0..3
        #pragma unroll
        for (int i = 0; i < 16; ++i) {
            const int c = cb + i * 4;
            const float4 v = *(const float4*)(xrow + (size_t)c * 16384 + lq);
            *(float4*)&xs[c][lq] = v;
        }
    }
    __syncthreads();

    // ---- stage 1: f[j] = b1[j] + sum_c xs[c][t] * W1[c*64+j] ----
    float f[64];
    #pragma unroll
    for (int j = 0; j < 64; ++j) f[j] = b1[j];

    #pragma unroll 4
    for (int c = 0; c < 64; ++c) {
        const float xc = xs[c][t];
        const float* w = W1 + c * 64;   // wave-uniform -> scalar loads
        #pragma unroll
        for (int j = 0; j < 64; ++j) f[j] = fmaf(xc, w[j], f[j]);
    }

    // ---- stage 2: 16 subpixels ----
    const float* Ay = W1 + 64 * 64;  // rel_y weights
    const float* Ax = W1 + 65 * 64;  // rel_x weights
    const float bb0 = b2[0], bb1 = b2[1], bb2 = b2[2];

    const int ox0 = (l0 + t) * 4;

    for (int ry = 0; ry < 4; ++ry) {   // runtime loop: keeps code size sane
        const float ay = (2 * ry - 3) * 0.25f;
        float p[3][4];                 // [ch][rx] — fully unrolled below => regs

        #pragma unroll
        for (int rx = 0; rx < 4; ++rx) {
            const float ax = (2 * rx - 3) * 0.25f;
            float p0 = bb0, p1 = bb1, p2 = bb2;
            #pragma unroll
            for (int j = 0; j < 64; ++j) {
                float h = fmaf(ay, Ay[j], f[j]);
                h = fmaf(ax, Ax[j], h);
                h = fmaxf(h, 0.0f);
                p0 = fmaf(h, W2[3 * j + 0], p0);
                p1 = fmaf(h, W2[3 * j + 1], p1);
                p2 = fmaf(h, W2[3 * j + 2], p2);
            }
            p[0][rx] = p0; p[1][rx] = p1; p[2][rx] = p2;
        }

        const int oy = 4 * k + ry;
        float* op = out + ((size_t)(b * 3) * 512 + oy) * 512 + ox0;
        #pragma unroll
        for (int ch = 0; ch < 3; ++ch) {
            float4 v;
            v.x = p[ch][0]; v.y = p[ch][1]; v.z = p[ch][2]; v.w = p[ch][3];
            *(float4*)(op + (size_t)ch * PLANE) = v;
        }
    }
}

extern "C" void kernel_launch(void* const* d_in, const int* in_sizes, int n_in,
                              void* d_out, int out_size, void* d_ws, size_t ws_size,
                              hipStream_t stream) {
    const float* x  = (const float*)d_in[0];
    const float* W1 = (const float*)d_in[1];
    const float* b1 = (const float*)d_in[2];
    const float* W2 = (const float*)d_in[3];
    const float* b2 = (const float*)d_in[4];
    float* out = (float*)d_out;

    // blocks: b(4) * k(128) * strips(2) = 1024, 64 threads each
    mlp_interp_kernel<<<1024, 64, 0, stream>>>(x, W1, b1, W2, b2, out);
}

// Round 2
// 115.098 us; speedup vs baseline: 1.0951x; 1.0951x over previous
//
#include <hip/hip_runtime.h>

// MLP_Interpolate: B=4, C=64, H=W=128, out 512x512, n_feat=64.
// Algebra: 4x nearest upsample => iy = oy>>2, ix = ox>>2 exactly;
// rel_y/rel_x depend only on (oy&3)/(ox&3), values (2r-3)/4.
// Per INPUT pixel: f[j] = b1[j] + sum_c x[b,c,k,l]*W1[c,j] (once), then 16
// subpixels: h = relu(f + ay*W1[64,:] + ax*W1[65,:]); pred = h@W2 + b2.
//
// R2: 4 waves/block (256 thr). Phase1 splits the j-dim across waves (no
// redundant work), f staged in LDS; phase2 splits ry across waves.
// 1024 blocks * 4 waves -> 4 waves/SIMD (was 1) to hide s_load/LDS latency.

#define PLANE (512 * 512)
#define PITCH 68   // 64 + 4 pad floats: lane stride 272B -> conflict-free b128

__global__ __launch_bounds__(256, 4) void mlp_interp_kernel(
    const float* __restrict__ x,   // [4,64,128,128]
    const float* __restrict__ W1,  // [66,64]
    const float* __restrict__ b1,  // [64]
    const float* __restrict__ W2,  // [64,3]
    const float* __restrict__ b2,  // [3]
    float* __restrict__ out)       // [4,3,512,512]
{
    __shared__ float xs[64][64];      // [c][l]   16 KiB
    __shared__ float fs[64][PITCH];   // [l][j]   17 KiB

    const int tid = threadIdx.x;
    const int w   = tid >> 6;         // wave 0..3
    const int t   = tid & 63;         // lane -> input pixel l0+t

    const int blk  = blockIdx.x;      // 0..1023
    const int lblk = blk & 1;         // 2 strips per row
    const int k    = (blk >> 1) & 127;
    const int b    = blk >> 8;
    const int l0   = lblk * 64;

    // ---- stage x tile [c][l0..l0+63] into LDS, float4-coalesced ----
    {
        const float* xrow = x + (((size_t)(b * 64) * 128 + k) * 128 + l0);
        const int lq = (tid & 15) * 4;   // column quad
        const int cb = tid >> 4;         // 0..15
        #pragma unroll
        for (int i = 0; i < 4; ++i) {
            const int c = cb + i * 16;
            *(float4*)&xs[c][lq] = *(const float4*)(xrow + (size_t)c * 16384 + lq);
        }
    }
    __syncthreads();

    // ---- phase 1: wave w computes f[16w..16w+16) for its lane's pixel ----
    {
        const int jb = w * 16;
        float f[16];
        #pragma unroll
        for (int jj = 0; jj < 16; ++jj) f[jj] = b1[jb + jj];

        #pragma unroll 8
        for (int c = 0; c < 64; ++c) {
            const float xc = xs[c][t];
            const float* wr = W1 + c * 64 + jb;   // wave-uniform -> s_load
            #pragma unroll
            for (int jj = 0; jj < 16; ++jj) f[jj] = fmaf(xc, wr[jj], f[jj]);
        }
        #pragma unroll
        for (int q = 0; q < 4; ++q) {
            float4 v;
            v.x = f[4*q]; v.y = f[4*q+1]; v.z = f[4*q+2]; v.w = f[4*q+3];
            *(float4*)&fs[t][jb + 4*q] = v;
        }
    }
    __syncthreads();

    // ---- phase 2: wave w handles ry = w for its lane's pixel ----
    {
        float f[64];
        #pragma unroll
        for (int q = 0; q < 16; ++q) {
            const float4 v = *(const float4*)&fs[t][4*q];
            f[4*q] = v.x; f[4*q+1] = v.y; f[4*q+2] = v.z; f[4*q+3] = v.w;
        }

        const float* Ay = W1 + 64 * 64;
        const float* Ax = W1 + 65 * 64;
        const float ay = (2 * w - 3) * 0.25f;

        // fold the ry term in-place (f dead afterwards -> no extra regs)
        #pragma unroll
        for (int j = 0; j < 64; ++j) f[j] = fmaf(ay, Ay[j], f[j]);

        const float bb0 = b2[0], bb1 = b2[1], bb2 = b2[2];
        float pch[3][4];

        #pragma unroll
        for (int rx = 0; rx < 4; ++rx) {
            const float ax = (2 * rx - 3) * 0.25f;
            float p0 = bb0, p1 = bb1, p2 = bb2;
            #pragma unroll
            for (int j = 0; j < 64; ++j) {
                float h = fmaf(ax, Ax[j], f[j]);
                h = fmaxf(h, 0.0f);
                p0 = fmaf(h, W2[3*j + 0], p0);
                p1 = fmaf(h, W2[3*j + 1], p1);
                p2 = fmaf(h, W2[3*j + 2], p2);
            }
            pch[0][rx] = p0; pch[1][rx] = p1; pch[2][rx] = p2;
        }

        const int oy  = 4 * k + w;
        const int ox0 = (l0 + t) * 4;
        float* op = out + ((size_t)(b * 3) * 512 + oy) * 512 + ox0;
        #pragma unroll
        for (int ch = 0; ch < 3; ++ch) {
            float4 v;
            v.x = pch[ch][0]; v.y = pch[ch][1]; v.z = pch[ch][2]; v.w = pch[ch][3];
            *(float4*)(op + (size_t)ch * PLANE) = v;
        }
    }
}

extern "C" void kernel_launch(void* const* d_in, const int* in_sizes, int n_in,
                              void* d_out, int out_size, void* d_ws, size_t ws_size,
                              hipStream_t stream) {
    const float* x  = (const float*)d_in[0];
    const float* W1 = (const float*)d_in[1];
    const float* b1 = (const float*)d_in[2];
    const float* W2 = (const float*)d_in[3];
    const float* b2 = (const float*)d_in[4];
    float* out = (float*)d_out;

    // blocks: b(4) * k(128) * strips(2) = 1024, 256 threads each
    mlp_interp_kernel<<<1024, 256, 0, stream>>>(x, W1, b1, W2, b2, out);
}

// Round 4
// 110.756 us; speedup vs baseline: 1.1380x; 1.0392x over previous
//
#include <hip/hip_runtime.h>

// MLP_Interpolate: B=4, C=64, H=W=128, out 512x512, n_feat=64.
// Algebra: 4x nearest upsample => iy = oy>>2, ix = ox>>2 exactly;
// rel_y/rel_x depend only on (oy&3)/(ox&3), values (2r-3)/4.
// Per INPUT pixel: f[j] = b1[j] + sum_c x[b,c,k,l]*W1[c,j] (once), then 16
// subpixels: h = relu(f + ay*W1[64,:] + ax*W1[65,:]); pred = h@W2 + b2.
//
// R3 (resubmit after broker timeout): 8 waves/block (512 thr), 64-pixel
// strip. Stage1 splits j 8 ways; stage2 splits (ry, rx-half). LDS 33.8KB ->
// 4 blocks/CU * 8 waves = 32 waves/CU (100% cap, was 50%).

#define PLANE (512 * 512)
#define PITCH 68   // 64 + 4 pad: 8-lane b128 groups land on distinct banks

__global__ __launch_bounds__(512, 8) void mlp_interp_kernel(
    const float* __restrict__ x,   // [4,64,128,128]
    const float* __restrict__ W1,  // [66,64]
    const float* __restrict__ b1,  // [64]
    const float* __restrict__ W2,  // [64,3]
    const float* __restrict__ b2,  // [3]
    float* __restrict__ out)       // [4,3,512,512]
{
    __shared__ float xs[64][64];      // [c][l]   16 KiB
    __shared__ float fs[64][PITCH];   // [l][j]   17 KiB

    const int tid = threadIdx.x;
    const int w   = tid >> 6;         // wave 0..7
    const int t   = tid & 63;         // lane -> input pixel l0+t

    const int blk  = blockIdx.x;      // 0..1023
    const int lblk = blk & 1;         // 2 strips per row
    const int k    = (blk >> 1) & 127;
    const int b    = blk >> 8;
    const int l0   = lblk * 64;

    // ---- stage x tile [c][l0..l0+63] into LDS, float4-coalesced ----
    {
        const float* xbase = x + (((size_t)(b * 64)) * 128 + k) * 128 + l0;
        #pragma unroll
        for (int i = 0; i < 2; ++i) {
            const int idx = i * 512 + tid;      // 0..1023
            const int c   = idx >> 4;           // 0..63
            const int lq  = (idx & 15) * 4;     // column quad
            *(float4*)&xs[c][lq] = *(const float4*)(xbase + (size_t)c * 16384 + lq);
        }
    }
    __syncthreads();

    // ---- stage 1: wave w computes f[8w..8w+8) for its lane's pixel ----
    {
        const int jb = w * 8;
        float f[8];
        #pragma unroll
        for (int jj = 0; jj < 8; ++jj) f[jj] = b1[jb + jj];

        #pragma unroll 8
        for (int c = 0; c < 64; ++c) {
            const float xc = xs[c][t];
            const float* wr = W1 + c * 64 + jb;   // wave-uniform -> s_load
            #pragma unroll
            for (int jj = 0; jj < 8; ++jj) f[jj] = fmaf(xc, wr[jj], f[jj]);
        }
        #pragma unroll
        for (int q = 0; q < 2; ++q) {
            float4 v;
            v.x = f[4*q]; v.y = f[4*q+1]; v.z = f[4*q+2]; v.w = f[4*q+3];
            *(float4*)&fs[t][jb + 4*q] = v;
        }
    }
    __syncthreads();

    // ---- stage 2: wave w handles (ry = w>>1, rx-half = w&1) ----
    {
        float f[64];
        #pragma unroll
        for (int q = 0; q < 16; ++q) {
            const float4 v = *(const float4*)&fs[t][4*q];
            f[4*q] = v.x; f[4*q+1] = v.y; f[4*q+2] = v.z; f[4*q+3] = v.w;
        }

        const float* Ay = W1 + 64 * 64;
        const float* Ax = W1 + 65 * 64;
        const int ry = w >> 1;
        const int rh = w & 1;
        const float ay = (2 * ry - 3) * 0.25f;

        // fold the ry term in-place
        #pragma unroll
        for (int j = 0; j < 64; ++j) f[j] = fmaf(ay, Ay[j], f[j]);

        const float bb0 = b2[0], bb1 = b2[1], bb2 = b2[2];
        float pch[3][2];

        #pragma unroll
        for (int r2 = 0; r2 < 2; ++r2) {
            const int rx = 2 * rh + r2;
            const float ax = (2 * rx - 3) * 0.25f;
            float p0 = bb0, p1 = bb1, p2 = bb2;
            #pragma unroll
            for (int j = 0; j < 64; ++j) {
                float h = fmaf(ax, Ax[j], f[j]);
                h = fmaxf(h, 0.0f);
                p0 = fmaf(h, W2[3*j + 0], p0);
                p1 = fmaf(h, W2[3*j + 1], p1);
                p2 = fmaf(h, W2[3*j + 2], p2);
            }
            pch[0][r2] = p0; pch[1][r2] = p1; pch[2][r2] = p2;
        }

        const int oy  = 4 * k + ry;
        const int ox0 = (l0 + t) * 4 + 2 * rh;
        float* op = out + ((size_t)(b * 3) * 512 + oy) * 512 + ox0;
        #pragma unroll
        for (int ch = 0; ch < 3; ++ch) {
            float2 v;
            v.x = pch[ch][0]; v.y = pch[ch][1];
            *(float2*)(op + (size_t)ch * PLANE) = v;
        }
    }
}

extern "C" void kernel_launch(void* const* d_in, const int* in_sizes, int n_in,
                              void* d_out, int out_size, void* d_ws, size_t ws_size,
                              hipStream_t stream) {
    const float* x  = (const float*)d_in[0];
    const float* W1 = (const float*)d_in[1];
    const float* b1 = (const float*)d_in[2];
    const float* W2 = (const float*)d_in[3];
    const float* b2 = (const float*)d_in[4];
    float* out = (float*)d_out;

    // blocks: b(4) * k(128) * strips(2) = 1024, 512 threads each
    mlp_interp_kernel<<<1024, 512, 0, stream>>>(x, W1, b1, W2, b2, out);
}

// Round 6
// 108.685 us; speedup vs baseline: 1.1597x; 1.0190x over previous
//
#include <hip/hip_runtime.h>

// MLP_Interpolate: B=4, C=64, H=W=128, out 512x512, n_feat=64.
// Algebra: 4x nearest upsample => iy = oy>>2, ix = ox>>2 exactly;
// rel_y/rel_x depend only on (oy&3)/(ox&3), values (2r-3)/4.
// Per INPUT pixel: f[j] = b1[j] + sum_c x[b,c,k,l]*W1[c,j] (once), then 16
// subpixels: h = relu(f + ay*W1[64,:] + ax*W1[65,:]); pred = h@W2 + b2.
//
// R5 (resubmit after broker timeout): fix R3/R4's register spill.
// launch_bounds(512,8) capped VGPR at 64 -> compiler allocated 32 and
// spilled f[64] (VALUBusy stuck at 23% despite 54% occupancy). Now: stage 2
// is j-chunked (f[16] live max, ~55 regs peak) and launch_bounds(512,6)
// caps at 80 VGPR -> no spill, 24 waves/CU.

#define PLANE (512 * 512)
#define PITCH 68   // 64 + 4 pad: conflict-free b128 reads of fs rows

__global__ __launch_bounds__(512, 6) void mlp_interp_kernel(
    const float* __restrict__ x,   // [4,64,128,128]
    const float* __restrict__ W1,  // [66,64]
    const float* __restrict__ b1,  // [64]
    const float* __restrict__ W2,  // [64,3]
    const float* __restrict__ b2,  // [3]
    float* __restrict__ out)       // [4,3,512,512]
{
    __shared__ float xs[64][64];      // [c][l]   16 KiB
    __shared__ float fs[64][PITCH];   // [l][j]   17 KiB

    const int tid = threadIdx.x;
    const int w   = tid >> 6;         // wave 0..7
    const int t   = tid & 63;         // lane -> input pixel l0+t

    const int blk  = blockIdx.x;      // 0..1023
    const int lblk = blk & 1;         // 2 strips per row
    const int k    = (blk >> 1) & 127;
    const int b    = blk >> 8;
    const int l0   = lblk * 64;

    // ---- stage x tile [c][l0..l0+63] into LDS, float4-coalesced ----
    {
        const float* xbase = x + (((size_t)(b * 64)) * 128 + k) * 128 + l0;
        #pragma unroll
        for (int i = 0; i < 2; ++i) {
            const int idx = i * 512 + tid;      // 0..1023
            const int c   = idx >> 4;           // 0..63
            const int lq  = (idx & 15) * 4;     // column quad
            *(float4*)&xs[c][lq] = *(const float4*)(xbase + (size_t)c * 16384 + lq);
        }
    }
    __syncthreads();

    // ---- stage 1: wave w computes f[8w..8w+8) for its lane's pixel ----
    {
        const int jb = w * 8;
        float f[8];
        #pragma unroll
        for (int jj = 0; jj < 8; ++jj) f[jj] = b1[jb + jj];

        #pragma unroll 8
        for (int c = 0; c < 64; ++c) {
            const float xc = xs[c][t];
            const float* wr = W1 + c * 64 + jb;
            #pragma unroll
            for (int jj = 0; jj < 8; ++jj) f[jj] = fmaf(xc, wr[jj], f[jj]);
        }
        #pragma unroll
        for (int q = 0; q < 2; ++q) {
            float4 v;
            v.x = f[4*q]; v.y = f[4*q+1]; v.z = f[4*q+2]; v.w = f[4*q+3];
            *(float4*)&fs[t][jb + 4*q] = v;
        }
    }
    __syncthreads();

    // ---- stage 2: wave w handles (ry = w>>1, rx-pair = w&1), j-chunked ----
    {
        const int ry = w >> 1;
        const int rh = w & 1;
        const float ay  = (2 * ry - 3) * 0.25f;
        const float ax0 = (2 * (2 * rh)     - 3) * 0.25f;
        const float ax1 = (2 * (2 * rh + 1) - 3) * 0.25f;

        const float* Ay = W1 + 64 * 64;
        const float* Ax = W1 + 65 * 64;

        float p00 = b2[0], p10 = b2[1], p20 = b2[2];   // rx even
        float p01 = b2[0], p11 = b2[1], p21 = b2[2];   // rx odd

        #pragma unroll
        for (int q = 0; q < 4; ++q) {
            float f[16];
            #pragma unroll
            for (int u = 0; u < 4; ++u) {
                const float4 v = *(const float4*)&fs[t][16*q + 4*u];
                f[4*u] = v.x; f[4*u+1] = v.y; f[4*u+2] = v.z; f[4*u+3] = v.w;
            }
            #pragma unroll
            for (int i = 0; i < 16; ++i) {
                const int j = 16*q + i;
                const float g  = fmaf(ay, Ay[j], f[i]);
                const float h0 = fmaxf(fmaf(ax0, Ax[j], g), 0.0f);
                const float h1 = fmaxf(fmaf(ax1, Ax[j], g), 0.0f);
                const float w0 = W2[3*j + 0];
                const float w1 = W2[3*j + 1];
                const float w2 = W2[3*j + 2];
                p00 = fmaf(h0, w0, p00); p10 = fmaf(h0, w1, p10); p20 = fmaf(h0, w2, p20);
                p01 = fmaf(h1, w0, p01); p11 = fmaf(h1, w1, p11); p21 = fmaf(h1, w2, p21);
            }
        }

        const int oy  = 4 * k + ry;
        const int ox0 = (l0 + t) * 4 + 2 * rh;
        float* op = out + ((size_t)(b * 3) * 512 + oy) * 512 + ox0;
        float2 v0; v0.x = p00; v0.y = p01;
        float2 v1; v1.x = p10; v1.y = p11;
        float2 v2; v2.x = p20; v2.y = p21;
        *(float2*)(op)             = v0;
        *(float2*)(op +     PLANE) = v1;
        *(float2*)(op + 2 * PLANE) = v2;
    }
}

extern "C" void kernel_launch(void* const* d_in, const int* in_sizes, int n_in,
                              void* d_out, int out_size, void* d_ws, size_t ws_size,
                              hipStream_t stream) {
    const float* x  = (const float*)d_in[0];
    const float* W1 = (const float*)d_in[1];
    const float* b1 = (const float*)d_in[2];
    const float* W2 = (const float*)d_in[3];
    const float* b2 = (const float*)d_in[4];
    float* out = (float*)d_out;

    // blocks: b(4) * k(128) * strips(2) = 1024, 512 threads each
    mlp_interp_kernel<<<1024, 512, 0, stream>>>(x, W1, b1, W2, b2, out);
}

// Round 7
// 84.749 us; speedup vs baseline: 1.4873x; 1.2824x over previous
//
#include <hip/hip_runtime.h>
#include <hip/hip_bf16.h>

// MLP_Interpolate: B=4, C=64, H=W=128, out 512x512, n_feat=64.
// Algebra: 4x nearest upsample => iy = oy>>2, ix = ox>>2 exactly;
// rel depends only on (oy&3)/(ox&3): values (2r-3)/4.
// Per INPUT pixel: f[j] = b1[j] + sum_c x*W1 (once); 16 subpixels:
// h = relu(f + ay*W1[64,:] + ax*W1[65,:]); pred = h@W2 + b2.
//
// R7: R1-R6 showed VALUBusy pinned at ~23% regardless of occupancy ->
// shared per-CU bottleneck = scalar L1 thrash (every wave streams 17KB of
// W1 via s_load through the 16KB scalar cache). Fix: stage 1 via bf16 MFMA
// (x, W1 through the VECTOR path; L1-cached, reused). Stage-2 weights are
// only 2.8KB -> scalar L1 now holds them. LDS 17.4KB -> 4 blocks/CU.

#define PLANE (512 * 512)
#define PITCH 68   // fs pitch: conflict-free b128 reads (measured 0 in R6)

typedef __attribute__((ext_vector_type(8))) short  short8;   // 8 x bf16
typedef __attribute__((ext_vector_type(4))) float  f32x4;

__device__ __forceinline__ short bf16_of(float f) {
    __hip_bfloat16 h = __float2bfloat16(f);   // RNE
    return *reinterpret_cast<short*>(&h);
}

__global__ __launch_bounds__(512, 8) void mlp_interp_kernel(
    const float* __restrict__ x,   // [4,64,128,128]
    const float* __restrict__ W1,  // [66,64]
    const float* __restrict__ b1,  // [64]
    const float* __restrict__ W2,  // [64,3]
    const float* __restrict__ b2,  // [3]
    float* __restrict__ out)       // [4,3,512,512]
{
    __shared__ float fs[64][PITCH];   // [pixel][j]  17.4 KiB

    const int tid = threadIdx.x;
    const int w   = tid >> 6;          // wave 0..7
    const int t   = tid & 63;          // lane

    const int blk  = blockIdx.x;       // 0..1023
    const int lblk = blk & 1;          // 2 strips per row
    const int k    = (blk >> 1) & 127;
    const int b    = blk >> 8;
    const int l0   = lblk * 64;

    // ================= stage 1: f = x @ W1[:64] + b1 via MFMA ==============
    // M=64 pixels, K=64 ch, N=64 units. 16 C-tiles (mt,nt); wave w owns
    // mt = w>>1, nt in {2*(w&1), 2*(w&1)+1}. Fragment pattern per m92/m89:
    // A row-major-K: lane holds row (l&15), k = 32ks+8g+i (g=l>>4);
    // B^T row-major-K: lane holds col j=16nt+(l&15), same k set;
    // C/D: col = l&15, row = 4g + reg.
    {
        const int lane16 = t & 15;
        const int g      = t >> 4;
        const int mt     = w >> 1;
        const int nt0    = (w & 1) * 2;

        // A-frags: x[b][c][k][l0 + 16mt + lane16], c = 32ks+8g+i
        const float* xbase = x + (((size_t)(b * 64)) * 128 + k) * 128
                               + l0 + 16 * mt + lane16;
        short8 afrag[2];
        #pragma unroll
        for (int ks = 0; ks < 2; ++ks) {
            float tmp[8];
            #pragma unroll
            for (int i = 0; i < 8; ++i)
                tmp[i] = xbase[(size_t)(32 * ks + 8 * g + i) * 16384];
            #pragma unroll
            for (int i = 0; i < 8; ++i) afrag[ks][i] = bf16_of(tmp[i]);
        }

        // B-frags + MFMA per nt
        #pragma unroll
        for (int ntp = 0; ntp < 2; ++ntp) {
            const int j = 16 * (nt0 + ntp) + lane16;
            short8 bfrag[2];
            #pragma unroll
            for (int ks = 0; ks < 2; ++ks) {
                float tmp[8];
                #pragma unroll
                for (int i = 0; i < 8; ++i)
                    tmp[i] = W1[(32 * ks + 8 * g + i) * 64 + j];
                #pragma unroll
                for (int i = 0; i < 8; ++i) bfrag[ks][i] = bf16_of(tmp[i]);
            }

            const float b1j = b1[j];
            f32x4 acc = {b1j, b1j, b1j, b1j};
            acc = __builtin_amdgcn_mfma_f32_16x16x32_bf16(afrag[0], bfrag[0], acc, 0, 0, 0);
            acc = __builtin_amdgcn_mfma_f32_16x16x32_bf16(afrag[1], bfrag[1], acc, 0, 0, 0);

            #pragma unroll
            for (int r = 0; r < 4; ++r)
                fs[16 * mt + 4 * g + r][j] = acc[r];
        }
    }
    __syncthreads();

    // ========== stage 2: wave w -> (ry = w>>1, rx-pair = w&1), j-chunked ===
    {
        const int ry = w >> 1;
        const int rh = w & 1;
        const float ay  = (2 * ry - 3) * 0.25f;
        const float ax0 = (2 * (2 * rh)     - 3) * 0.25f;
        const float ax1 = (2 * (2 * rh + 1) - 3) * 0.25f;

        const float* Ay = W1 + 64 * 64;
        const float* Ax = W1 + 65 * 64;

        float p00 = b2[0], p10 = b2[1], p20 = b2[2];   // rx even
        float p01 = b2[0], p11 = b2[1], p21 = b2[2];   // rx odd

        #pragma unroll
        for (int q = 0; q < 4; ++q) {
            float f[16];
            #pragma unroll
            for (int u = 0; u < 4; ++u) {
                const float4 v = *(const float4*)&fs[t][16 * q + 4 * u];
                f[4*u] = v.x; f[4*u+1] = v.y; f[4*u+2] = v.z; f[4*u+3] = v.w;
            }
            #pragma unroll
            for (int i = 0; i < 16; ++i) {
                const int j = 16 * q + i;
                const float g2 = fmaf(ay, Ay[j], f[i]);
                const float h0 = fmaxf(fmaf(ax0, Ax[j], g2), 0.0f);
                const float h1 = fmaxf(fmaf(ax1, Ax[j], g2), 0.0f);
                const float w0 = W2[3*j + 0];
                const float w1 = W2[3*j + 1];
                const float w2 = W2[3*j + 2];
                p00 = fmaf(h0, w0, p00); p10 = fmaf(h0, w1, p10); p20 = fmaf(h0, w2, p20);
                p01 = fmaf(h1, w0, p01); p11 = fmaf(h1, w1, p11); p21 = fmaf(h1, w2, p21);
            }
        }

        const int oy  = 4 * k + ry;
        const int ox0 = (l0 + t) * 4 + 2 * rh;
        float* op = out + ((size_t)(b * 3) * 512 + oy) * 512 + ox0;
        float2 v0; v0.x = p00; v0.y = p01;
        float2 v1; v1.x = p10; v1.y = p11;
        float2 v2; v2.x = p20; v2.y = p21;
        *(float2*)(op)             = v0;
        *(float2*)(op +     PLANE) = v1;
        *(float2*)(op + 2 * PLANE) = v2;
    }
}

extern "C" void kernel_launch(void* const* d_in, const int* in_sizes, int n_in,
                              void* d_out, int out_size, void* d_ws, size_t ws_size,
                              hipStream_t stream) {
    const float* x  = (const float*)d_in[0];
    const float* W1 = (const float*)d_in[1];
    const float* b1 = (const float*)d_in[2];
    const float* W2 = (const float*)d_in[3];
    const float* b2 = (const float*)d_in[4];
    float* out = (float*)d_out;

    // blocks: b(4) * k(128) * strips(2) = 1024, 512 threads each
    mlp_interp_kernel<<<1024, 512, 0, stream>>>(x, W1, b1, W2, b2, out);
}

// Round 9
// 82.450 us; speedup vs baseline: 1.5287x; 1.0279x over previous
//
#include <hip/hip_runtime.h>
#include <hip/hip_bf16.h>

// MLP_Interpolate: B=4, C=64, H=W=128, out 512x512, n_feat=64.
// Per INPUT pixel: f[j] = b1[j] + sum_c x*W1 (once, via bf16 MFMA); 16
// subpixels: h = relu(f + ay*W1[64,:] + ax*W1[65,:]); pred = h@W2 + b2.
//
// R8 (resubmit after broker timeout): R7 (~20us est) still ~2x above the
// ~9us issue+HBM floor. Grid was 1024x512thr = exactly 4 blocks/CU one-shot
// -> all blocks phase-locked: x-fetch latency and barrier drains fully
// exposed. Now 2048 blocks x 256 thr (32-pixel quarter-strips, 8.7KB LDS,
// launch_bounds(256,6) -> 6 blocks/CU + dynamic refill): blocks on a CU sit
// in different phases, so stage-1 HBM latency hides under other blocks'
// stage-2 VALU.

#define PLANE (512 * 512)
#define PITCH 68   // fs pitch: 2-way max on b128 reads (free); 0 conflicts measured

typedef __attribute__((ext_vector_type(8))) short  short8;   // 8 x bf16
typedef __attribute__((ext_vector_type(4))) float  f32x4;

__device__ __forceinline__ short bf16_of(float f) {
    __hip_bfloat16 h = __float2bfloat16(f);   // RNE
    return *reinterpret_cast<short*>(&h);
}

__global__ __launch_bounds__(256, 6) void mlp_interp_kernel(
    const float* __restrict__ x,   // [4,64,128,128]
    const float* __restrict__ W1,  // [66,64]
    const float* __restrict__ b1,  // [64]
    const float* __restrict__ W2,  // [64,3]
    const float* __restrict__ b2,  // [3]
    float* __restrict__ out)       // [4,3,512,512]
{
    __shared__ float fs[32][PITCH];   // [pixel][j]  8.7 KiB

    const int tid = threadIdx.x;
    const int w   = tid >> 6;          // wave 0..3
    const int t   = tid & 63;          // lane

    const int blk  = blockIdx.x;       // 0..2047
    const int lblk = blk & 3;          // 4 quarter-strips of 32 px
    const int k    = (blk >> 2) & 127; // input row
    const int b    = blk >> 9;         // batch
    const int l0   = lblk * 32;

    // ============ stage 1: f = x @ W1[:64] + b1 via bf16 MFMA =============
    // M=32 px (2 mtiles), N=64 units (4 ntiles), K=64 ch. 8 C-tiles over 4
    // waves: wave w -> mt = w>>1, nt in {2*(w&1), 2*(w&1)+1}.
    // Fragments (verified R7, absmax 0.0039): A row-major-K lane=(row l&15,
    // k=32ks+8g+i, g=l>>4); B^T row-major-K lane=(col j, same k);
    // C/D: col=l&15, row=4g+reg.
    {
        const int lane16 = t & 15;
        const int g      = t >> 4;
        const int mt     = w >> 1;
        const int nt0    = (w & 1) * 2;

        const float* xbase = x + (((size_t)(b * 64)) * 128 + k) * 128
                               + l0 + 16 * mt + lane16;
        short8 afrag[2];
        #pragma unroll
        for (int ks = 0; ks < 2; ++ks) {
            float tmp[8];
            #pragma unroll
            for (int i = 0; i < 8; ++i)
                tmp[i] = xbase[(size_t)(32 * ks + 8 * g + i) * 16384];
            #pragma unroll
            for (int i = 0; i < 8; ++i) afrag[ks][i] = bf16_of(tmp[i]);
        }

        #pragma unroll
        for (int ntp = 0; ntp < 2; ++ntp) {
            const int j = 16 * (nt0 + ntp) + lane16;
            short8 bfrag[2];
            #pragma unroll
            for (int ks = 0; ks < 2; ++ks) {
                float tmp[8];
                #pragma unroll
                for (int i = 0; i < 8; ++i)
                    tmp[i] = W1[(32 * ks + 8 * g + i) * 64 + j];
                #pragma unroll
                for (int i = 0; i < 8; ++i) bfrag[ks][i] = bf16_of(tmp[i]);
            }

            const float b1j = b1[j];
            f32x4 acc = {b1j, b1j, b1j, b1j};
            acc = __builtin_amdgcn_mfma_f32_16x16x32_bf16(afrag[0], bfrag[0], acc, 0, 0, 0);
            acc = __builtin_amdgcn_mfma_f32_16x16x32_bf16(afrag[1], bfrag[1], acc, 0, 0, 0);

            #pragma unroll
            for (int r = 0; r < 4; ++r)
                fs[16 * mt + 4 * g + r][j] = acc[r];
        }
    }
    __syncthreads();

    // ====== stage 2: wave w = ry; lane -> (pixel = t&31, rx-half = t>>5) ==
    {
        const int p  = t & 31;
        const int rh = t >> 5;
        const int ry = w;
        const float ay  = (2 * ry - 3) * 0.25f;
        const float ax0 = (2 * (2 * rh)     - 3) * 0.25f;
        const float ax1 = (2 * (2 * rh + 1) - 3) * 0.25f;

        const float* Ay = W1 + 64 * 64;
        const float* Ax = W1 + 65 * 64;

        float p00 = b2[0], p10 = b2[1], p20 = b2[2];   // rx even
        float p01 = b2[0], p11 = b2[1], p21 = b2[2];   // rx odd

        #pragma unroll
        for (int q = 0; q < 4; ++q) {
            float f[16];
            #pragma unroll
            for (int u = 0; u < 4; ++u) {
                const float4 v = *(const float4*)&fs[p][16 * q + 4 * u];
                f[4*u] = v.x; f[4*u+1] = v.y; f[4*u+2] = v.z; f[4*u+3] = v.w;
            }
            #pragma unroll
            for (int i = 0; i < 16; ++i) {
                const int j = 16 * q + i;
                const float g2 = fmaf(ay, Ay[j], f[i]);
                const float h0 = fmaxf(fmaf(ax0, Ax[j], g2), 0.0f);
                const float h1 = fmaxf(fmaf(ax1, Ax[j], g2), 0.0f);
                const float w0 = W2[3*j + 0];
                const float w1 = W2[3*j + 1];
                const float w2 = W2[3*j + 2];
                p00 = fmaf(h0, w0, p00); p10 = fmaf(h0, w1, p10); p20 = fmaf(h0, w2, p20);
                p01 = fmaf(h1, w0, p01); p11 = fmaf(h1, w1, p11); p21 = fmaf(h1, w2, p21);
            }
        }

        const int oy  = 4 * k + ry;
        const int ox0 = (l0 + p) * 4 + 2 * rh;
        float* op = out + ((size_t)(b * 3) * 512 + oy) * 512 + ox0;
        float2 v0; v0.x = p00; v0.y = p01;
        float2 v1; v1.x = p10; v1.y = p11;
        float2 v2; v2.x = p20; v2.y = p21;
        *(float2*)(op)             = v0;
        *(float2*)(op +     PLANE) = v1;
        *(float2*)(op + 2 * PLANE) = v2;
    }
}

extern "C" void kernel_launch(void* const* d_in, const int* in_sizes, int n_in,
                              void* d_out, int out_size, void* d_ws, size_t ws_size,
                              hipStream_t stream) {
    const float* x  = (const float*)d_in[0];
    const float* W1 = (const float*)d_in[1];
    const float* b1 = (const float*)d_in[2];
    const float* W2 = (const float*)d_in[3];
    const float* b2 = (const float*)d_in[4];
    float* out = (float*)d_out;

    // blocks: b(4) * k(128) * quarter-strips(4) = 2048, 256 threads each
    mlp_interp_kernel<<<2048, 256, 0, stream>>>(x, W1, b1, W2, b2, out);
}